// Round 1
// baseline (1240.891 us; speedup 1.0000x reference)
//
#include <hip/hip_runtime.h>
#include <cstdint>
#include <cstddef>

#define D_MODEL 1024
#define D_FF    4096
#define N_EXPERTS 8
#define TOPK_    2
#define NTOK    8192
#define NSLOT   (NTOK*TOPK_)

#define BM 128
#define BN 128
#define BK 64

typedef __attribute__((ext_vector_type(8))) short bf16x8;
typedef __attribute__((ext_vector_type(4))) float f32x4;
typedef unsigned int u32;

__device__ __forceinline__ unsigned short f2bf(float f){
  union { float f; u32 u; } v; v.f = f;
  u32 u = v.u;
  u32 r = (u + 0x7FFFu + ((u >> 16) & 1u)) >> 16;
  return (unsigned short)r;
}

__device__ __forceinline__ float gelu_exact(float x){
  return 0.5f * x * (1.0f + erff(x * 0.70710678118654752f));
}

__device__ __forceinline__ void gload_lds16(const void* g, void* l){
  __builtin_amdgcn_global_load_lds(
      (const __attribute__((address_space(1))) u32*)g,
      (__attribute__((address_space(3))) u32*)l, 16, 0, 0);
}

// ---------------- conversion kernels ----------------

__global__ void convert_x_kernel(const float* __restrict__ x,
                                 unsigned short* __restrict__ xb){
  size_t i = ((size_t)blockIdx.x * blockDim.x + threadIdx.x) * 4;
  float4 v = *(const float4*)(x + i);
  u32 a = (u32)f2bf(v.x) | ((u32)f2bf(v.y) << 16);
  u32 b = (u32)f2bf(v.z) | ((u32)f2bf(v.w) << 16);
  uint2 pk; pk.x = a; pk.y = b;
  *(uint2*)(xb + i) = pk;
}

// in: [E][R][C] fp32  ->  out: [E][C][R] bf16
__global__ void transpose_convert_kernel(const float* __restrict__ in,
                                         unsigned short* __restrict__ out,
                                         int R, int C){
  __shared__ float tile[32][33];
  const int e  = blockIdx.z;
  const int c0 = blockIdx.x * 32;
  const int r0 = blockIdx.y * 32;
  const int tx = threadIdx.x;       // 0..31
  const int ty = threadIdx.y;       // 0..7
  const size_t base = (size_t)e * R * C;
  #pragma unroll
  for (int i = 0; i < 32; i += 8)
    tile[ty + i][tx] = in[base + (size_t)(r0 + ty + i) * C + (c0 + tx)];
  __syncthreads();
  #pragma unroll
  for (int i = 0; i < 32; i += 8)
    out[base + (size_t)(c0 + ty + i) * R + (r0 + tx)] = f2bf(tile[tx][ty + i]);
}

// ---------------- router ----------------

__global__ void router_kernel(const float* __restrict__ x,
                              const float* __restrict__ Wr,
                              const float* __restrict__ br,
                              int* __restrict__ counts,
                              int* __restrict__ topk_idx,
                              float* __restrict__ topk_gate){
  const int n = blockIdx.x;
  const int lane = threadIdx.x;      // 64 threads
  const float* xr = x + (size_t)n * D_MODEL;
  float acc[N_EXPERTS];
  #pragma unroll
  for (int e = 0; e < N_EXPERTS; e++) acc[e] = 0.f;
  #pragma unroll
  for (int i = 0; i < D_MODEL / 64; i++){
    int d = lane + i * 64;
    float xv = xr[d];
    const float* wr = Wr + (size_t)d * N_EXPERTS;
    #pragma unroll
    for (int e = 0; e < N_EXPERTS; e++) acc[e] += xv * wr[e];
  }
  #pragma unroll
  for (int e = 0; e < N_EXPERTS; e++){
    float v = acc[e];
    for (int o = 32; o > 0; o >>= 1) v += __shfl_xor(v, o, 64);
    acc[e] = v;
  }
  if (lane == 0){
    float logits[N_EXPERTS];
    float m = -1e30f;
    #pragma unroll
    for (int e = 0; e < N_EXPERTS; e++){
      logits[e] = acc[e] + br[e];
      m = fmaxf(m, logits[e]);
    }
    float p[N_EXPERTS]; float Z = 0.f;
    #pragma unroll
    for (int e = 0; e < N_EXPERTS; e++){ p[e] = expf(logits[e] - m); Z += p[e]; }
    #pragma unroll
    for (int e = 0; e < N_EXPERTS; e++) p[e] /= Z;
    int i0 = 0;
    #pragma unroll
    for (int e = 1; e < N_EXPERTS; e++) if (p[e] > p[i0]) i0 = e;
    int i1 = (i0 == 0) ? 1 : 0;
    #pragma unroll
    for (int e = 0; e < N_EXPERTS; e++){
      if (e == i0) continue;
      if (p[e] > p[i1]) i1 = e;
    }
    float s = p[i0] + p[i1] + 1e-9f;
    topk_idx[n * 2 + 0] = i0;
    topk_idx[n * 2 + 1] = i1;
    topk_gate[n * 2 + 0] = p[i0] / s;
    topk_gate[n * 2 + 1] = p[i1] / s;
    atomicAdd(&counts[i0], 1);
    atomicAdd(&counts[i1], 1);
  }
}

__global__ void prefix_kernel(const int* __restrict__ counts,
                              int* __restrict__ offsets,
                              int* __restrict__ cursor){
  if (threadIdx.x == 0 && blockIdx.x == 0){
    int o = 0;
    for (int e = 0; e < N_EXPERTS; e++){
      offsets[e] = o; cursor[e] = o; o += counts[e];
    }
  }
}

__global__ void assign_kernel(const int* __restrict__ topk_idx,
                              const float* __restrict__ topk_gate,
                              int* __restrict__ cursor,
                              int* __restrict__ bucket_token,
                              float* __restrict__ bucket_gate){
  int n = blockIdx.x * blockDim.x + threadIdx.x;
  if (n >= NTOK) return;
  #pragma unroll
  for (int k = 0; k < TOPK_; k++){
    int e = topk_idx[n * 2 + k];
    float g = topk_gate[n * 2 + k];
    int s = atomicAdd(&cursor[e], 1);
    bucket_token[s] = n;
    bucket_gate[s] = g;
  }
}

// ---------------- grouped GEMM 1: h = gelu(x @ W1 + b1) ----------------
// A: xb [NTOK][1024] bf16 (rows gathered via bucket_token)
// B: W1t [E][4096][1024] bf16 (N-major, K contiguous)
// out: h [NSLOT][4096] bf16

__global__ __launch_bounds__(256) void gemm1_kernel(
    const unsigned short* __restrict__ xb,
    const unsigned short* __restrict__ W1t,
    const float* __restrict__ b1,
    const int* __restrict__ bucket_token,
    const int* __restrict__ offsets,
    const int* __restrict__ counts,
    unsigned short* __restrict__ h){
  const int e     = blockIdx.z;
  const int mtile = blockIdx.y;
  const int ntile = blockIdx.x;
  const int count = counts[e];
  if (mtile * BM >= count) return;
  const int off = offsets[e];

  __shared__ unsigned short As[BM][BK];
  __shared__ unsigned short Bs[BN][BK];

  const int tid  = threadIdx.x;
  const int lane = tid & 63;
  const int wave = tid >> 6;

  // staging: per inst, wave covers 8 rows x 64 cols (lane -> row=lane>>3, chunk=lane&7)
  const int srow = wave * 8 + (lane >> 3);
  const int scol = (lane & 7) * 8;

  int arow[4];
  #pragma unroll
  for (int j = 0; j < 4; j++){
    int m = mtile * BM + j * 32 + srow;
    arow[j] = bucket_token[off + min(m, count - 1)];
  }
  const unsigned short* Bbase = W1t + ((size_t)e * D_FF + (size_t)ntile * BN) * D_MODEL;

  const f32x4 zero = {0.f, 0.f, 0.f, 0.f};
  f32x4 acc[4][4];
  #pragma unroll
  for (int i = 0; i < 4; i++)
    #pragma unroll
    for (int j = 0; j < 4; j++) acc[i][j] = zero;

  const int wm = (wave >> 1) * 64;
  const int wn = (wave & 1) * 64;
  const int frag_m = lane & 15;
  const int frag_k = (lane >> 4) * 8;

  for (int k0 = 0; k0 < D_MODEL; k0 += BK){
    __syncthreads();
    #pragma unroll
    for (int j = 0; j < 4; j++)
      gload_lds16(xb + (size_t)arow[j] * D_MODEL + k0 + scol, &As[j * 32 + srow][scol]);
    #pragma unroll
    for (int j = 0; j < 4; j++)
      gload_lds16(Bbase + (size_t)(j * 32 + srow) * D_MODEL + k0 + scol, &Bs[j * 32 + srow][scol]);
    __syncthreads();
    #pragma unroll
    for (int kk = 0; kk < BK; kk += 32){
      bf16x8 a[4], b[4];
      #pragma unroll
      for (int i = 0; i < 4; i++)
        a[i] = *(const bf16x8*)&As[wm + i * 16 + frag_m][kk + frag_k];
      #pragma unroll
      for (int j = 0; j < 4; j++)
        b[j] = *(const bf16x8*)&Bs[wn + j * 16 + frag_m][kk + frag_k];
      #pragma unroll
      for (int i = 0; i < 4; i++)
        #pragma unroll
        for (int j = 0; j < 4; j++)
          acc[i][j] = __builtin_amdgcn_mfma_f32_16x16x32_bf16(a[i], b[j], acc[i][j], 0, 0, 0);
    }
  }

  const float* bias = b1 + (size_t)e * D_FF + (size_t)ntile * BN;
  #pragma unroll
  for (int i = 0; i < 4; i++){
    #pragma unroll
    for (int r = 0; r < 4; r++){
      int mrel = wm + i * 16 + (lane >> 4) * 4 + r;
      int m = mtile * BM + mrel;
      if (m >= count) continue;
      size_t hrow = (size_t)(off + m) * D_FF + (size_t)ntile * BN;
      #pragma unroll
      for (int j = 0; j < 4; j++){
        int nrel = wn + j * 16 + (lane & 15);
        float v = acc[i][j][r] + bias[nrel];
        h[hrow + nrel] = f2bf(gelu_exact(v));
      }
    }
  }
}

// ---------------- grouped GEMM 2: out[tok] += g * (h @ W2 + b2) ----------------

__global__ __launch_bounds__(256) void gemm2_kernel(
    const unsigned short* __restrict__ h,
    const unsigned short* __restrict__ W2t,   // [E][1024][4096]
    const float* __restrict__ b2,
    const int* __restrict__ bucket_token,
    const float* __restrict__ bucket_gate,
    const int* __restrict__ offsets,
    const int* __restrict__ counts,
    float* __restrict__ out){
  const int e     = blockIdx.z;
  const int mtile = blockIdx.y;
  const int ntile = blockIdx.x;
  const int count = counts[e];
  if (mtile * BM >= count) return;
  const int off = offsets[e];

  __shared__ unsigned short As[BM][BK];
  __shared__ unsigned short Bs[BN][BK];

  const int tid  = threadIdx.x;
  const int lane = tid & 63;
  const int wave = tid >> 6;

  const int srow = wave * 8 + (lane >> 3);
  const int scol = (lane & 7) * 8;

  size_t aslot[4];
  #pragma unroll
  for (int j = 0; j < 4; j++){
    int m = mtile * BM + j * 32 + srow;
    aslot[j] = (size_t)(off + min(m, count - 1));
  }
  const unsigned short* Bbase = W2t + ((size_t)e * D_MODEL + (size_t)ntile * BN) * D_FF;

  const f32x4 zero = {0.f, 0.f, 0.f, 0.f};
  f32x4 acc[4][4];
  #pragma unroll
  for (int i = 0; i < 4; i++)
    #pragma unroll
    for (int j = 0; j < 4; j++) acc[i][j] = zero;

  const int wm = (wave >> 1) * 64;
  const int wn = (wave & 1) * 64;
  const int frag_m = lane & 15;
  const int frag_k = (lane >> 4) * 8;

  for (int k0 = 0; k0 < D_FF; k0 += BK){
    __syncthreads();
    #pragma unroll
    for (int j = 0; j < 4; j++)
      gload_lds16(h + aslot[j] * D_FF + k0 + scol, &As[j * 32 + srow][scol]);
    #pragma unroll
    for (int j = 0; j < 4; j++)
      gload_lds16(Bbase + (size_t)(j * 32 + srow) * D_FF + k0 + scol, &Bs[j * 32 + srow][scol]);
    __syncthreads();
    #pragma unroll
    for (int kk = 0; kk < BK; kk += 32){
      bf16x8 a[4], b[4];
      #pragma unroll
      for (int i = 0; i < 4; i++)
        a[i] = *(const bf16x8*)&As[wm + i * 16 + frag_m][kk + frag_k];
      #pragma unroll
      for (int j = 0; j < 4; j++)
        b[j] = *(const bf16x8*)&Bs[wn + j * 16 + frag_m][kk + frag_k];
      #pragma unroll
      for (int i = 0; i < 4; i++)
        #pragma unroll
        for (int j = 0; j < 4; j++)
          acc[i][j] = __builtin_amdgcn_mfma_f32_16x16x32_bf16(a[i], b[j], acc[i][j], 0, 0, 0);
    }
  }

  const float* bias = b2 + (size_t)e * D_MODEL + (size_t)ntile * BN;
  #pragma unroll
  for (int i = 0; i < 4; i++){
    #pragma unroll
    for (int r = 0; r < 4; r++){
      int mrel = wm + i * 16 + (lane >> 4) * 4 + r;
      int m = mtile * BM + mrel;
      if (m >= count) continue;
      int slot = off + m;
      int tok = bucket_token[slot];
      float g = bucket_gate[slot];
      float* orow = out + (size_t)tok * D_MODEL + (size_t)ntile * BN;
      #pragma unroll
      for (int j = 0; j < 4; j++){
        int nrel = wn + j * 16 + (lane & 15);
        atomicAdd(&orow[nrel], g * (acc[i][j][r] + bias[nrel]));
      }
    }
  }
}

// ---------------- launch ----------------

extern "C" void kernel_launch(void* const* d_in, const int* in_sizes, int n_in,
                              void* d_out, int out_size, void* d_ws, size_t ws_size,
                              hipStream_t stream) {
  (void)in_sizes; (void)n_in; (void)ws_size;
  const float* x  = (const float*)d_in[0];
  const float* Wr = (const float*)d_in[1];
  const float* br = (const float*)d_in[2];
  const float* W1 = (const float*)d_in[3];
  const float* b1 = (const float*)d_in[4];
  const float* W2 = (const float*)d_in[5];
  const float* b2 = (const float*)d_in[6];
  float* out = (float*)d_out;

  char* ws = (char*)d_ws;
  size_t p = 0;
  auto alloc = [&](size_t bytes) -> void* {
    void* r = ws + p;
    p = (p + bytes + 255) & ~(size_t)255;
    return r;
  };

  int*   counts       = (int*)  alloc(N_EXPERTS * sizeof(int));
  int*   offsets      = (int*)  alloc(N_EXPERTS * sizeof(int));
  int*   cursor       = (int*)  alloc(N_EXPERTS * sizeof(int));
  int*   topk_idx     = (int*)  alloc((size_t)NTOK * 2 * sizeof(int));
  float* topk_gate    = (float*)alloc((size_t)NTOK * 2 * sizeof(float));
  int*   bucket_token = (int*)  alloc((size_t)NSLOT * sizeof(int));
  float* bucket_gate  = (float*)alloc((size_t)NSLOT * sizeof(float));
  unsigned short* xb  = (unsigned short*)alloc((size_t)NTOK * D_MODEL * 2);
  unsigned short* W1t = (unsigned short*)alloc((size_t)N_EXPERTS * D_MODEL * D_FF * 2);
  unsigned short* W2t = (unsigned short*)alloc((size_t)N_EXPERTS * D_MODEL * D_FF * 2);
  unsigned short* hb  = (unsigned short*)alloc((size_t)NSLOT * D_FF * 2);

  hipMemsetAsync(counts, 0, N_EXPERTS * sizeof(int), stream);
  hipMemsetAsync(d_out, 0, (size_t)out_size * sizeof(float), stream);

  convert_x_kernel<<<(NTOK * D_MODEL) / (4 * 256), 256, 0, stream>>>(x, xb);
  transpose_convert_kernel<<<dim3(D_FF / 32, D_MODEL / 32, N_EXPERTS), dim3(32, 8), 0, stream>>>(
      W1, W1t, D_MODEL, D_FF);
  transpose_convert_kernel<<<dim3(D_MODEL / 32, D_FF / 32, N_EXPERTS), dim3(32, 8), 0, stream>>>(
      W2, W2t, D_FF, D_MODEL);
  router_kernel<<<NTOK, 64, 0, stream>>>(x, Wr, br, counts, topk_idx, topk_gate);
  prefix_kernel<<<1, 64, 0, stream>>>(counts, offsets, cursor);
  assign_kernel<<<NTOK / 256, 256, 0, stream>>>(topk_idx, topk_gate, cursor, bucket_token, bucket_gate);
  gemm1_kernel<<<dim3(D_FF / BN, NTOK / BM, N_EXPERTS), 256, 0, stream>>>(
      xb, W1t, b1, bucket_token, offsets, counts, hb);
  gemm2_kernel<<<dim3(D_MODEL / BN, NTOK / BM, N_EXPERTS), 256, 0, stream>>>(
      hb, W2t, b2, bucket_token, bucket_gate, offsets, counts, out);
}

// Round 2
// 1188.513 us; speedup vs baseline: 1.0441x; 1.0441x over previous
//
#include <hip/hip_runtime.h>
#include <cstdint>
#include <cstddef>

#define D_MODEL 1024
#define D_FF    4096
#define N_EXPERTS 8
#define TOPK_    2
#define NTOK    8192
#define NSLOT   (NTOK*TOPK_)
#define MAXTILES 136

#define BM 128
#define BN 128
#define BK 64

typedef __attribute__((ext_vector_type(8))) short bf16x8;
typedef __attribute__((ext_vector_type(4))) float f32x4;
typedef unsigned int u32;

__device__ __forceinline__ unsigned short f2bf(float f){
  union { float f; u32 u; } v; v.f = f;
  u32 u = v.u;
  u32 r = (u + 0x7FFFu + ((u >> 16) & 1u)) >> 16;
  return (unsigned short)r;
}

__device__ __forceinline__ float gelu_exact(float x){
  return 0.5f * x * (1.0f + erff(x * 0.70710678118654752f));
}

__device__ __forceinline__ void gload_lds16(const void* g, void* l){
  __builtin_amdgcn_global_load_lds(
      (const __attribute__((address_space(1))) u32*)g,
      (__attribute__((address_space(3))) u32*)l, 16, 0, 0);
}

// ---------------- conversion kernels ----------------

__global__ void convert_x_kernel(const float* __restrict__ x,
                                 unsigned short* __restrict__ xb){
  size_t i = ((size_t)blockIdx.x * blockDim.x + threadIdx.x) * 4;
  float4 v = *(const float4*)(x + i);
  u32 a = (u32)f2bf(v.x) | ((u32)f2bf(v.y) << 16);
  u32 b = (u32)f2bf(v.z) | ((u32)f2bf(v.w) << 16);
  uint2 pk; pk.x = a; pk.y = b;
  *(uint2*)(xb + i) = pk;
}

// in: [E][R][C] fp32  ->  out: [E][C][R] bf16
__global__ void transpose_convert_kernel(const float* __restrict__ in,
                                         unsigned short* __restrict__ out,
                                         int R, int C){
  __shared__ float tile[32][33];
  const int e  = blockIdx.z;
  const int c0 = blockIdx.x * 32;
  const int r0 = blockIdx.y * 32;
  const int tx = threadIdx.x;       // 0..31
  const int ty = threadIdx.y;       // 0..7
  const size_t base = (size_t)e * R * C;
  #pragma unroll
  for (int i = 0; i < 32; i += 8)
    tile[ty + i][tx] = in[base + (size_t)(r0 + ty + i) * C + (c0 + tx)];
  __syncthreads();
  #pragma unroll
  for (int i = 0; i < 32; i += 8)
    out[base + (size_t)(c0 + ty + i) * R + (r0 + tx)] = f2bf(tile[tx][ty + i]);
}

// ---------------- router ----------------

__global__ void router_kernel(const float* __restrict__ x,
                              const float* __restrict__ Wr,
                              const float* __restrict__ br,
                              int* __restrict__ counts,
                              int* __restrict__ topk_idx,
                              float* __restrict__ topk_gate){
  const int n = blockIdx.x;
  const int lane = threadIdx.x;      // 64 threads
  const float* xr = x + (size_t)n * D_MODEL;
  float acc[N_EXPERTS];
  #pragma unroll
  for (int e = 0; e < N_EXPERTS; e++) acc[e] = 0.f;
  #pragma unroll
  for (int i = 0; i < D_MODEL / 64; i++){
    int d = lane + i * 64;
    float xv = xr[d];
    const float* wr = Wr + (size_t)d * N_EXPERTS;
    #pragma unroll
    for (int e = 0; e < N_EXPERTS; e++) acc[e] += xv * wr[e];
  }
  #pragma unroll
  for (int e = 0; e < N_EXPERTS; e++){
    float v = acc[e];
    for (int o = 32; o > 0; o >>= 1) v += __shfl_xor(v, o, 64);
    acc[e] = v;
  }
  if (lane == 0){
    float logits[N_EXPERTS];
    float m = -1e30f;
    #pragma unroll
    for (int e = 0; e < N_EXPERTS; e++){
      logits[e] = acc[e] + br[e];
      m = fmaxf(m, logits[e]);
    }
    float p[N_EXPERTS]; float Z = 0.f;
    #pragma unroll
    for (int e = 0; e < N_EXPERTS; e++){ p[e] = expf(logits[e] - m); Z += p[e]; }
    #pragma unroll
    for (int e = 0; e < N_EXPERTS; e++) p[e] /= Z;
    int i0 = 0;
    #pragma unroll
    for (int e = 1; e < N_EXPERTS; e++) if (p[e] > p[i0]) i0 = e;
    int i1 = (i0 == 0) ? 1 : 0;
    #pragma unroll
    for (int e = 0; e < N_EXPERTS; e++){
      if (e == i0) continue;
      if (p[e] > p[i1]) i1 = e;
    }
    float s = p[i0] + p[i1] + 1e-9f;
    topk_idx[n * 2 + 0] = i0;
    topk_idx[n * 2 + 1] = i1;
    topk_gate[n * 2 + 0] = p[i0] / s;
    topk_gate[n * 2 + 1] = p[i1] / s;
    atomicAdd(&counts[i0], 1);
    atomicAdd(&counts[i1], 1);
  }
}

__global__ void prefix_kernel(const int* __restrict__ counts,
                              int* __restrict__ offsets,
                              int* __restrict__ cursor,
                              int* __restrict__ tile_e,
                              int* __restrict__ tile_m){
  if (threadIdx.x == 0 && blockIdx.x == 0){
    int o = 0;
    for (int e = 0; e < N_EXPERTS; e++){
      offsets[e] = o; cursor[e] = o; o += counts[e];
    }
    int t = 0;
    for (int e = 0; e < N_EXPERTS; e++)
      for (int m = 0; m * BM < counts[e]; m++){
        tile_e[t] = e; tile_m[t] = m; t++;
      }
    for (; t < MAXTILES; t++){ tile_e[t] = -1; tile_m[t] = 0; }
  }
}

__global__ void assign_kernel(const int* __restrict__ topk_idx,
                              const float* __restrict__ topk_gate,
                              int* __restrict__ cursor,
                              int* __restrict__ bucket_token,
                              float* __restrict__ bucket_gate,
                              int* __restrict__ slot_of){
  int n = blockIdx.x * blockDim.x + threadIdx.x;
  if (n >= NTOK) return;
  #pragma unroll
  for (int k = 0; k < TOPK_; k++){
    int e = topk_idx[n * 2 + k];
    float g = topk_gate[n * 2 + k];
    int s = atomicAdd(&cursor[e], 1);
    bucket_token[s] = n;
    bucket_gate[s] = g;
    slot_of[n * 2 + k] = s;
  }
}

// ---------------- grouped GEMM 1: h = gelu(x @ W1 + b1) ----------------
// LDS tiles use XOR-swizzle: LDS slot (row, chunk c) holds global chunk
// c ^ (row & 7). Chunks are 8 bf16 = 16 B. Staging keeps the wave-linear
// LDS write order required by global_load_lds; only the *global* source
// chunk per lane is permuted.

__global__ __launch_bounds__(256) void gemm1_kernel(
    const unsigned short* __restrict__ xb,
    const unsigned short* __restrict__ W1t,
    const float* __restrict__ b1,
    const int* __restrict__ bucket_token,
    const int* __restrict__ offsets,
    const int* __restrict__ counts,
    const int* __restrict__ tile_e,
    const int* __restrict__ tile_m,
    unsigned short* __restrict__ h){
  const int e = tile_e[blockIdx.y];
  if (e < 0) return;
  const int mtile = tile_m[blockIdx.y];
  const int ntile = blockIdx.x;
  const int count = counts[e];
  const int off = offsets[e];

  __shared__ unsigned short As[BM][BK];
  __shared__ unsigned short Bs[BN][BK];

  const int tid  = threadIdx.x;
  const int lane = tid & 63;
  const int wave = tid >> 6;

  // staging: per inst, wave covers 8 rows x 8 chunks; lane -> row=lane>>3,
  // LDS chunk = lane&7, global chunk = (lane&7) ^ (lane>>3)
  const int srow   = wave * 8 + (lane >> 3);
  const int scol_l = (lane & 7) * 8;                       // LDS element offset
  const int scol_g = (((lane & 7) ^ (lane >> 3)) * 8);     // global element offset

  int arow[4];
  #pragma unroll
  for (int j = 0; j < 4; j++){
    int m = mtile * BM + j * 32 + srow;
    arow[j] = bucket_token[off + min(m, count - 1)];
  }
  const unsigned short* Bbase = W1t + ((size_t)e * D_FF + (size_t)ntile * BN) * D_MODEL;

  const f32x4 zero = {0.f, 0.f, 0.f, 0.f};
  f32x4 acc[4][4];
  #pragma unroll
  for (int i = 0; i < 4; i++)
    #pragma unroll
    for (int j = 0; j < 4; j++) acc[i][j] = zero;

  const int wm = (wave >> 1) * 64;
  const int wn = (wave & 1) * 64;
  const int frag_m = lane & 15;

  for (int k0 = 0; k0 < D_MODEL; k0 += BK){
    __syncthreads();
    #pragma unroll
    for (int j = 0; j < 4; j++)
      gload_lds16(xb + (size_t)arow[j] * D_MODEL + k0 + scol_g, &As[j * 32 + srow][scol_l]);
    #pragma unroll
    for (int j = 0; j < 4; j++)
      gload_lds16(Bbase + (size_t)(j * 32 + srow) * D_MODEL + k0 + scol_g, &Bs[j * 32 + srow][scol_l]);
    __syncthreads();
    #pragma unroll
    for (int kk = 0; kk < BK; kk += 32){
      // global chunk index this lane needs; row&7 == lane&7 for all fragment rows
      const int ck = ((((kk >> 3) + (lane >> 4)) ^ (lane & 7)) * 8);
      bf16x8 a[4], b[4];
      #pragma unroll
      for (int i = 0; i < 4; i++)
        a[i] = *(const bf16x8*)&As[wm + i * 16 + frag_m][ck];
      #pragma unroll
      for (int j = 0; j < 4; j++)
        b[j] = *(const bf16x8*)&Bs[wn + j * 16 + frag_m][ck];
      #pragma unroll
      for (int i = 0; i < 4; i++)
        #pragma unroll
        for (int j = 0; j < 4; j++)
          acc[i][j] = __builtin_amdgcn_mfma_f32_16x16x32_bf16(a[i], b[j], acc[i][j], 0, 0, 0);
    }
  }

  const float* bias = b1 + (size_t)e * D_FF + (size_t)ntile * BN;
  #pragma unroll
  for (int i = 0; i < 4; i++){
    #pragma unroll
    for (int r = 0; r < 4; r++){
      int mrel = wm + i * 16 + (lane >> 4) * 4 + r;
      int m = mtile * BM + mrel;
      if (m >= count) continue;
      size_t hrow = (size_t)(off + m) * D_FF + (size_t)ntile * BN;
      #pragma unroll
      for (int j = 0; j < 4; j++){
        int nrel = wn + j * 16 + (lane & 15);
        float v = acc[i][j][r] + bias[nrel];
        h[hrow + nrel] = f2bf(gelu_exact(v));
      }
    }
  }
}

// ---------------- grouped GEMM 2: y[slot] = g * (h @ W2 + b2) ----------------

__global__ __launch_bounds__(256) void gemm2_kernel(
    const unsigned short* __restrict__ h,
    const unsigned short* __restrict__ W2t,   // [E][1024][4096]
    const float* __restrict__ b2,
    const float* __restrict__ bucket_gate,
    const int* __restrict__ offsets,
    const int* __restrict__ counts,
    const int* __restrict__ tile_e,
    const int* __restrict__ tile_m,
    float* __restrict__ y){
  const int e = tile_e[blockIdx.y];
  if (e < 0) return;
  const int mtile = tile_m[blockIdx.y];
  const int ntile = blockIdx.x;
  const int count = counts[e];
  const int off = offsets[e];

  __shared__ unsigned short As[BM][BK];
  __shared__ unsigned short Bs[BN][BK];

  const int tid  = threadIdx.x;
  const int lane = tid & 63;
  const int wave = tid >> 6;

  const int srow   = wave * 8 + (lane >> 3);
  const int scol_l = (lane & 7) * 8;
  const int scol_g = (((lane & 7) ^ (lane >> 3)) * 8);

  size_t aslot[4];
  #pragma unroll
  for (int j = 0; j < 4; j++){
    int m = mtile * BM + j * 32 + srow;
    aslot[j] = (size_t)(off + min(m, count - 1));
  }
  const unsigned short* Bbase = W2t + ((size_t)e * D_MODEL + (size_t)ntile * BN) * D_FF;

  const f32x4 zero = {0.f, 0.f, 0.f, 0.f};
  f32x4 acc[4][4];
  #pragma unroll
  for (int i = 0; i < 4; i++)
    #pragma unroll
    for (int j = 0; j < 4; j++) acc[i][j] = zero;

  const int wm = (wave >> 1) * 64;
  const int wn = (wave & 1) * 64;
  const int frag_m = lane & 15;

  for (int k0 = 0; k0 < D_FF; k0 += BK){
    __syncthreads();
    #pragma unroll
    for (int j = 0; j < 4; j++)
      gload_lds16(h + aslot[j] * D_FF + k0 + scol_g, &As[j * 32 + srow][scol_l]);
    #pragma unroll
    for (int j = 0; j < 4; j++)
      gload_lds16(Bbase + (size_t)(j * 32 + srow) * D_FF + k0 + scol_g, &Bs[j * 32 + srow][scol_l]);
    __syncthreads();
    #pragma unroll
    for (int kk = 0; kk < BK; kk += 32){
      const int ck = ((((kk >> 3) + (lane >> 4)) ^ (lane & 7)) * 8);
      bf16x8 a[4], b[4];
      #pragma unroll
      for (int i = 0; i < 4; i++)
        a[i] = *(const bf16x8*)&As[wm + i * 16 + frag_m][ck];
      #pragma unroll
      for (int j = 0; j < 4; j++)
        b[j] = *(const bf16x8*)&Bs[wn + j * 16 + frag_m][ck];
      #pragma unroll
      for (int i = 0; i < 4; i++)
        #pragma unroll
        for (int j = 0; j < 4; j++)
          acc[i][j] = __builtin_amdgcn_mfma_f32_16x16x32_bf16(a[i], b[j], acc[i][j], 0, 0, 0);
    }
  }

  const float* bias = b2 + (size_t)e * D_MODEL + (size_t)ntile * BN;
  #pragma unroll
  for (int i = 0; i < 4; i++){
    #pragma unroll
    for (int r = 0; r < 4; r++){
      int mrel = wm + i * 16 + (lane >> 4) * 4 + r;
      int m = mtile * BM + mrel;
      if (m >= count) continue;
      int slot = off + m;
      float g = bucket_gate[slot];
      float* yrow = y + (size_t)slot * D_MODEL + (size_t)ntile * BN;
      #pragma unroll
      for (int j = 0; j < 4; j++){
        int nrel = wn + j * 16 + (lane & 15);
        yrow[nrel] = g * (acc[i][j][r] + bias[nrel]);
      }
    }
  }
}

// ---------------- combine: out[t] = y[slot0(t)] + y[slot1(t)] ----------------

__global__ void combine_kernel(const float* __restrict__ y,
                               const int* __restrict__ slot_of,
                               float* __restrict__ out){
  const int t = blockIdx.x;
  const int d = threadIdx.x * 4;
  const int s0 = slot_of[t * 2 + 0];
  const int s1 = slot_of[t * 2 + 1];
  float4 v0 = *(const float4*)(y + (size_t)s0 * D_MODEL + d);
  float4 v1 = *(const float4*)(y + (size_t)s1 * D_MODEL + d);
  float4 r;
  r.x = v0.x + v1.x; r.y = v0.y + v1.y;
  r.z = v0.z + v1.z; r.w = v0.w + v1.w;
  *(float4*)(out + (size_t)t * D_MODEL + d) = r;
}

// ---------------- launch ----------------

extern "C" void kernel_launch(void* const* d_in, const int* in_sizes, int n_in,
                              void* d_out, int out_size, void* d_ws, size_t ws_size,
                              hipStream_t stream) {
  (void)in_sizes; (void)n_in; (void)ws_size; (void)out_size;
  const float* x  = (const float*)d_in[0];
  const float* Wr = (const float*)d_in[1];
  const float* br = (const float*)d_in[2];
  const float* W1 = (const float*)d_in[3];
  const float* b1 = (const float*)d_in[4];
  const float* W2 = (const float*)d_in[5];
  const float* b2 = (const float*)d_in[6];
  float* out = (float*)d_out;

  char* ws = (char*)d_ws;
  size_t p = 0;
  auto alloc = [&](size_t bytes) -> void* {
    void* r = ws + p;
    p = (p + bytes + 255) & ~(size_t)255;
    return r;
  };

  int*   counts       = (int*)  alloc(N_EXPERTS * sizeof(int));
  int*   offsets      = (int*)  alloc(N_EXPERTS * sizeof(int));
  int*   cursor       = (int*)  alloc(N_EXPERTS * sizeof(int));
  int*   tile_e       = (int*)  alloc(MAXTILES * sizeof(int));
  int*   tile_m       = (int*)  alloc(MAXTILES * sizeof(int));
  int*   topk_idx     = (int*)  alloc((size_t)NTOK * 2 * sizeof(int));
  float* topk_gate    = (float*)alloc((size_t)NTOK * 2 * sizeof(float));
  int*   bucket_token = (int*)  alloc((size_t)NSLOT * sizeof(int));
  float* bucket_gate  = (float*)alloc((size_t)NSLOT * sizeof(float));
  int*   slot_of      = (int*)  alloc((size_t)NTOK * 2 * sizeof(int));
  unsigned short* xb  = (unsigned short*)alloc((size_t)NTOK * D_MODEL * 2);
  unsigned short* W1t = (unsigned short*)alloc((size_t)N_EXPERTS * D_MODEL * D_FF * 2);
  unsigned short* W2t = (unsigned short*)alloc((size_t)N_EXPERTS * D_MODEL * D_FF * 2);
  unsigned short* hb  = (unsigned short*)alloc((size_t)NSLOT * D_FF * 2);
  // y aliases W1t: W1t (64 MB) is dead once gemm1 completes; y needs
  // NSLOT*D_MODEL*4 = 64 MB. Sequential-stream ordering makes this safe.
  float* y = (float*)W1t;

  hipMemsetAsync(counts, 0, N_EXPERTS * sizeof(int), stream);

  convert_x_kernel<<<(NTOK * D_MODEL) / (4 * 256), 256, 0, stream>>>(x, xb);
  transpose_convert_kernel<<<dim3(D_FF / 32, D_MODEL / 32, N_EXPERTS), dim3(32, 8), 0, stream>>>(
      W1, W1t, D_MODEL, D_FF);
  router_kernel<<<NTOK, 64, 0, stream>>>(x, Wr, br, counts, topk_idx, topk_gate);
  prefix_kernel<<<1, 64, 0, stream>>>(counts, offsets, cursor, tile_e, tile_m);
  assign_kernel<<<NTOK / 256, 256, 0, stream>>>(topk_idx, topk_gate, cursor,
                                                bucket_token, bucket_gate, slot_of);
  gemm1_kernel<<<dim3(D_FF / BN, MAXTILES), 256, 0, stream>>>(
      xb, W1t, b1, bucket_token, offsets, counts, tile_e, tile_m, hb);
  transpose_convert_kernel<<<dim3(D_MODEL / 32, D_FF / 32, N_EXPERTS), dim3(32, 8), 0, stream>>>(
      W2, W2t, D_FF, D_MODEL);
  gemm2_kernel<<<dim3(D_MODEL / BN, MAXTILES), 256, 0, stream>>>(
      hb, W2t, b2, bucket_gate, offsets, counts, tile_e, tile_m, y);
  combine_kernel<<<NTOK, 256, 0, stream>>>(y, slot_of, out);
}

// Round 3
// 974.427 us; speedup vs baseline: 1.2735x; 1.2197x over previous
//
#include <hip/hip_runtime.h>
#include <cstdint>
#include <cstddef>

#define D_MODEL 1024
#define D_FF    4096
#define N_EXPERTS 8
#define TOPK_    2
#define NTOK    8192
#define NSLOT   (NTOK*TOPK_)
#define MAXTILES 136

#define BM 128
#define BN 128
#define BK 64

typedef __attribute__((ext_vector_type(8))) short bf16x8;
typedef __attribute__((ext_vector_type(4))) float f32x4;
typedef unsigned int u32;

__device__ __forceinline__ unsigned short f2bf(float f){
  union { float f; u32 u; } v; v.f = f;
  u32 u = v.u;
  u32 r = (u + 0x7FFFu + ((u >> 16) & 1u)) >> 16;
  return (unsigned short)r;
}

// gelu(x) = 0.5 x (1 + erf(x/sqrt2)); erf via Abramowitz-Stegun 7.1.26,
// |erf error| <= 1.5e-7 absolute -> indistinguishable from libm at bf16.
// ~16 VALU instrs vs ~100 for __ocml erff.
__device__ __forceinline__ float gelu_fast(float x){
  float z = fabsf(x) * 0.70710678118654752f;
  float t = __builtin_amdgcn_rcpf(fmaf(0.3275911f, z, 1.0f));
  float poly = t * (0.254829592f + t * (-0.284496736f + t * (1.421413741f +
               t * (-1.453152027f + t * 1.061405429f))));
  float e = __expf(-z * z);
  float erf_abs = fmaf(-poly, e, 1.0f);
  float erfv = copysignf(erf_abs, x);
  return 0.5f * x * (1.0f + erfv);
}

__device__ __forceinline__ void gload_lds16(const void* g, void* l){
  __builtin_amdgcn_global_load_lds(
      (const __attribute__((address_space(1))) u32*)g,
      (__attribute__((address_space(3))) u32*)l, 16, 0, 0);
}

// ---------------- conversion kernels ----------------

__global__ void convert_x_kernel(const float* __restrict__ x,
                                 unsigned short* __restrict__ xb){
  size_t i = ((size_t)blockIdx.x * blockDim.x + threadIdx.x) * 4;
  float4 v = *(const float4*)(x + i);
  u32 a = (u32)f2bf(v.x) | ((u32)f2bf(v.y) << 16);
  u32 b = (u32)f2bf(v.z) | ((u32)f2bf(v.w) << 16);
  uint2 pk; pk.x = a; pk.y = b;
  *(uint2*)(xb + i) = pk;
}

// in: [E][R][C] fp32  ->  out: [E][C][R] bf16
__global__ void transpose_convert_kernel(const float* __restrict__ in,
                                         unsigned short* __restrict__ out,
                                         int R, int C){
  __shared__ float tile[32][33];
  const int e  = blockIdx.z;
  const int c0 = blockIdx.x * 32;
  const int r0 = blockIdx.y * 32;
  const int tx = threadIdx.x;       // 0..31
  const int ty = threadIdx.y;       // 0..7
  const size_t base = (size_t)e * R * C;
  #pragma unroll
  for (int i = 0; i < 32; i += 8)
    tile[ty + i][tx] = in[base + (size_t)(r0 + ty + i) * C + (c0 + tx)];
  __syncthreads();
  #pragma unroll
  for (int i = 0; i < 32; i += 8)
    out[base + (size_t)(c0 + ty + i) * R + (r0 + tx)] = f2bf(tile[tx][ty + i]);
}

// ---------------- router ----------------

__global__ void router_kernel(const float* __restrict__ x,
                              const float* __restrict__ Wr,
                              const float* __restrict__ br,
                              int* __restrict__ counts,
                              int* __restrict__ topk_idx,
                              float* __restrict__ topk_gate){
  const int n = blockIdx.x;
  const int lane = threadIdx.x;      // 64 threads
  const float* xr = x + (size_t)n * D_MODEL;
  float acc[N_EXPERTS];
  #pragma unroll
  for (int e = 0; e < N_EXPERTS; e++) acc[e] = 0.f;
  #pragma unroll
  for (int i = 0; i < D_MODEL / 64; i++){
    int d = lane + i * 64;
    float xv = xr[d];
    const float* wr = Wr + (size_t)d * N_EXPERTS;
    #pragma unroll
    for (int e = 0; e < N_EXPERTS; e++) acc[e] += xv * wr[e];
  }
  #pragma unroll
  for (int e = 0; e < N_EXPERTS; e++){
    float v = acc[e];
    for (int o = 32; o > 0; o >>= 1) v += __shfl_xor(v, o, 64);
    acc[e] = v;
  }
  if (lane == 0){
    float logits[N_EXPERTS];
    float m = -1e30f;
    #pragma unroll
    for (int e = 0; e < N_EXPERTS; e++){
      logits[e] = acc[e] + br[e];
      m = fmaxf(m, logits[e]);
    }
    float p[N_EXPERTS]; float Z = 0.f;
    #pragma unroll
    for (int e = 0; e < N_EXPERTS; e++){ p[e] = expf(logits[e] - m); Z += p[e]; }
    #pragma unroll
    for (int e = 0; e < N_EXPERTS; e++) p[e] /= Z;
    int i0 = 0;
    #pragma unroll
    for (int e = 1; e < N_EXPERTS; e++) if (p[e] > p[i0]) i0 = e;
    int i1 = (i0 == 0) ? 1 : 0;
    #pragma unroll
    for (int e = 0; e < N_EXPERTS; e++){
      if (e == i0) continue;
      if (p[e] > p[i1]) i1 = e;
    }
    float s = p[i0] + p[i1] + 1e-9f;
    topk_idx[n * 2 + 0] = i0;
    topk_idx[n * 2 + 1] = i1;
    topk_gate[n * 2 + 0] = p[i0] / s;
    topk_gate[n * 2 + 1] = p[i1] / s;
    atomicAdd(&counts[i0], 1);
    atomicAdd(&counts[i1], 1);
  }
}

__global__ void prefix_kernel(const int* __restrict__ counts,
                              int* __restrict__ offsets,
                              int* __restrict__ cursor,
                              int* __restrict__ tile_e,
                              int* __restrict__ tile_m){
  if (threadIdx.x == 0 && blockIdx.x == 0){
    int o = 0;
    for (int e = 0; e < N_EXPERTS; e++){
      offsets[e] = o; cursor[e] = o; o += counts[e];
    }
    int t = 0;
    for (int e = 0; e < N_EXPERTS; e++)
      for (int m = 0; m * BM < counts[e]; m++){
        tile_e[t] = e; tile_m[t] = m; t++;
      }
    for (; t < MAXTILES; t++){ tile_e[t] = -1; tile_m[t] = 0; }
  }
}

__global__ void assign_kernel(const int* __restrict__ topk_idx,
                              const float* __restrict__ topk_gate,
                              int* __restrict__ cursor,
                              int* __restrict__ bucket_token,
                              float* __restrict__ bucket_gate,
                              int* __restrict__ slot_of){
  int n = blockIdx.x * blockDim.x + threadIdx.x;
  if (n >= NTOK) return;
  #pragma unroll
  for (int k = 0; k < TOPK_; k++){
    int e = topk_idx[n * 2 + k];
    float g = topk_gate[n * 2 + k];
    int s = atomicAdd(&cursor[e], 1);
    bucket_token[s] = n;
    bucket_gate[s] = g;
    slot_of[n * 2 + k] = s;
  }
}

// ---------------- grouped GEMM 1: h = gelu(x @ W1 + b1) ----------------
// LDS tiles use XOR-swizzle: LDS slot (row, chunk c) holds global chunk
// c ^ (row & 7). Chunks are 8 bf16 = 16 B. Staging keeps the wave-linear
// LDS write order required by global_load_lds; only the *global* source
// chunk per lane is permuted. Conflict-free (verified: SQ_LDS_BANK_CONFLICT=0).

__global__ __launch_bounds__(256, 3) void gemm1_kernel(
    const unsigned short* __restrict__ xb,
    const unsigned short* __restrict__ W1t,
    const float* __restrict__ b1,
    const int* __restrict__ bucket_token,
    const int* __restrict__ offsets,
    const int* __restrict__ counts,
    const int* __restrict__ tile_e,
    const int* __restrict__ tile_m,
    unsigned short* __restrict__ h){
  const int e = tile_e[blockIdx.y];
  if (e < 0) return;
  const int mtile = tile_m[blockIdx.y];
  const int ntile = blockIdx.x;
  const int count = counts[e];
  const int off = offsets[e];

  __shared__ unsigned short As[BM][BK];
  __shared__ unsigned short Bs[BN][BK];

  const int tid  = threadIdx.x;
  const int lane = tid & 63;
  const int wave = tid >> 6;

  const int srow   = wave * 8 + (lane >> 3);
  const int scol_l = (lane & 7) * 8;                       // LDS element offset
  const int scol_g = (((lane & 7) ^ (lane >> 3)) * 8);     // global element offset

  int arow[4];
  #pragma unroll
  for (int j = 0; j < 4; j++){
    int m = mtile * BM + j * 32 + srow;
    arow[j] = bucket_token[off + min(m, count - 1)];
  }
  const unsigned short* Bbase = W1t + ((size_t)e * D_FF + (size_t)ntile * BN) * D_MODEL;

  const f32x4 zero = {0.f, 0.f, 0.f, 0.f};
  f32x4 acc[4][4];
  #pragma unroll
  for (int i = 0; i < 4; i++)
    #pragma unroll
    for (int j = 0; j < 4; j++) acc[i][j] = zero;

  const int wm = (wave >> 1) * 64;
  const int wn = (wave & 1) * 64;
  const int frag_m = lane & 15;

  for (int k0 = 0; k0 < D_MODEL; k0 += BK){
    __syncthreads();
    #pragma unroll
    for (int j = 0; j < 4; j++)
      gload_lds16(xb + (size_t)arow[j] * D_MODEL + k0 + scol_g, &As[j * 32 + srow][scol_l]);
    #pragma unroll
    for (int j = 0; j < 4; j++)
      gload_lds16(Bbase + (size_t)(j * 32 + srow) * D_MODEL + k0 + scol_g, &Bs[j * 32 + srow][scol_l]);
    __syncthreads();
    #pragma unroll
    for (int kk = 0; kk < BK; kk += 32){
      const int ck = ((((kk >> 3) + (lane >> 4)) ^ (lane & 7)) * 8);
      bf16x8 a[4], b[4];
      #pragma unroll
      for (int i = 0; i < 4; i++)
        a[i] = *(const bf16x8*)&As[wm + i * 16 + frag_m][ck];
      #pragma unroll
      for (int j = 0; j < 4; j++)
        b[j] = *(const bf16x8*)&Bs[wn + j * 16 + frag_m][ck];
      #pragma unroll
      for (int i = 0; i < 4; i++)
        #pragma unroll
        for (int j = 0; j < 4; j++)
          acc[i][j] = __builtin_amdgcn_mfma_f32_16x16x32_bf16(a[i], b[j], acc[i][j], 0, 0, 0);
    }
  }

  const float* bias = b1 + (size_t)e * D_FF + (size_t)ntile * BN;
  #pragma unroll
  for (int i = 0; i < 4; i++){
    #pragma unroll
    for (int r = 0; r < 4; r++){
      int mrel = wm + i * 16 + (lane >> 4) * 4 + r;
      int m = mtile * BM + mrel;
      if (m >= count) continue;
      size_t hrow = (size_t)(off + m) * D_FF + (size_t)ntile * BN;
      #pragma unroll
      for (int j = 0; j < 4; j++){
        int nrel = wn + j * 16 + (lane & 15);
        float v = acc[i][j][r] + bias[nrel];
        h[hrow + nrel] = f2bf(gelu_fast(v));
      }
    }
  }
}

// ---------------- grouped GEMM 2: y[slot] = g * (h @ W2 + b2) ----------------

__global__ __launch_bounds__(256, 3) void gemm2_kernel(
    const unsigned short* __restrict__ h,
    const unsigned short* __restrict__ W2t,   // [E][1024][4096]
    const float* __restrict__ b2,
    const float* __restrict__ bucket_gate,
    const int* __restrict__ offsets,
    const int* __restrict__ counts,
    const int* __restrict__ tile_e,
    const int* __restrict__ tile_m,
    float* __restrict__ y){
  const int e = tile_e[blockIdx.y];
  if (e < 0) return;
  const int mtile = tile_m[blockIdx.y];
  const int ntile = blockIdx.x;
  const int count = counts[e];
  const int off = offsets[e];

  __shared__ unsigned short As[BM][BK];
  __shared__ unsigned short Bs[BN][BK];

  const int tid  = threadIdx.x;
  const int lane = tid & 63;
  const int wave = tid >> 6;

  const int srow   = wave * 8 + (lane >> 3);
  const int scol_l = (lane & 7) * 8;
  const int scol_g = (((lane & 7) ^ (lane >> 3)) * 8);

  size_t aslot[4];
  #pragma unroll
  for (int j = 0; j < 4; j++){
    int m = mtile * BM + j * 32 + srow;
    aslot[j] = (size_t)(off + min(m, count - 1));
  }
  const unsigned short* Bbase = W2t + ((size_t)e * D_MODEL + (size_t)ntile * BN) * D_FF;

  const f32x4 zero = {0.f, 0.f, 0.f, 0.f};
  f32x4 acc[4][4];
  #pragma unroll
  for (int i = 0; i < 4; i++)
    #pragma unroll
    for (int j = 0; j < 4; j++) acc[i][j] = zero;

  const int wm = (wave >> 1) * 64;
  const int wn = (wave & 1) * 64;
  const int frag_m = lane & 15;

  for (int k0 = 0; k0 < D_FF; k0 += BK){
    __syncthreads();
    #pragma unroll
    for (int j = 0; j < 4; j++)
      gload_lds16(h + aslot[j] * D_FF + k0 + scol_g, &As[j * 32 + srow][scol_l]);
    #pragma unroll
    for (int j = 0; j < 4; j++)
      gload_lds16(Bbase + (size_t)(j * 32 + srow) * D_FF + k0 + scol_g, &Bs[j * 32 + srow][scol_l]);
    __syncthreads();
    #pragma unroll
    for (int kk = 0; kk < BK; kk += 32){
      const int ck = ((((kk >> 3) + (lane >> 4)) ^ (lane & 7)) * 8);
      bf16x8 a[4], b[4];
      #pragma unroll
      for (int i = 0; i < 4; i++)
        a[i] = *(const bf16x8*)&As[wm + i * 16 + frag_m][ck];
      #pragma unroll
      for (int j = 0; j < 4; j++)
        b[j] = *(const bf16x8*)&Bs[wn + j * 16 + frag_m][ck];
      #pragma unroll
      for (int i = 0; i < 4; i++)
        #pragma unroll
        for (int j = 0; j < 4; j++)
          acc[i][j] = __builtin_amdgcn_mfma_f32_16x16x32_bf16(a[i], b[j], acc[i][j], 0, 0, 0);
    }
  }

  const float* bias = b2 + (size_t)e * D_MODEL + (size_t)ntile * BN;
  #pragma unroll
  for (int i = 0; i < 4; i++){
    #pragma unroll
    for (int r = 0; r < 4; r++){
      int mrel = wm + i * 16 + (lane >> 4) * 4 + r;
      int m = mtile * BM + mrel;
      if (m >= count) continue;
      int slot = off + m;
      float g = bucket_gate[slot];
      float* yrow = y + (size_t)slot * D_MODEL + (size_t)ntile * BN;
      #pragma unroll
      for (int j = 0; j < 4; j++){
        int nrel = wn + j * 16 + (lane & 15);
        yrow[nrel] = g * (acc[i][j][r] + bias[nrel]);
      }
    }
  }
}

// ---------------- combine: out[t] = y[slot0(t)] + y[slot1(t)] ----------------

__global__ void combine_kernel(const float* __restrict__ y,
                               const int* __restrict__ slot_of,
                               float* __restrict__ out){
  const int t = blockIdx.x;
  const int d = threadIdx.x * 4;
  const int s0 = slot_of[t * 2 + 0];
  const int s1 = slot_of[t * 2 + 1];
  float4 v0 = *(const float4*)(y + (size_t)s0 * D_MODEL + d);
  float4 v1 = *(const float4*)(y + (size_t)s1 * D_MODEL + d);
  float4 r;
  r.x = v0.x + v1.x; r.y = v0.y + v1.y;
  r.z = v0.z + v1.z; r.w = v0.w + v1.w;
  *(float4*)(out + (size_t)t * D_MODEL + d) = r;
}

// ---------------- launch ----------------

extern "C" void kernel_launch(void* const* d_in, const int* in_sizes, int n_in,
                              void* d_out, int out_size, void* d_ws, size_t ws_size,
                              hipStream_t stream) {
  (void)in_sizes; (void)n_in; (void)ws_size; (void)out_size;
  const float* x  = (const float*)d_in[0];
  const float* Wr = (const float*)d_in[1];
  const float* br = (const float*)d_in[2];
  const float* W1 = (const float*)d_in[3];
  const float* b1 = (const float*)d_in[4];
  const float* W2 = (const float*)d_in[5];
  const float* b2 = (const float*)d_in[6];
  float* out = (float*)d_out;

  char* ws = (char*)d_ws;
  size_t p = 0;
  auto alloc = [&](size_t bytes) -> void* {
    void* r = ws + p;
    p = (p + bytes + 255) & ~(size_t)255;
    return r;
  };

  int*   counts       = (int*)  alloc(N_EXPERTS * sizeof(int));
  int*   offsets      = (int*)  alloc(N_EXPERTS * sizeof(int));
  int*   cursor       = (int*)  alloc(N_EXPERTS * sizeof(int));
  int*   tile_e       = (int*)  alloc(MAXTILES * sizeof(int));
  int*   tile_m       = (int*)  alloc(MAXTILES * sizeof(int));
  int*   topk_idx     = (int*)  alloc((size_t)NTOK * 2 * sizeof(int));
  float* topk_gate    = (float*)alloc((size_t)NTOK * 2 * sizeof(float));
  int*   bucket_token = (int*)  alloc((size_t)NSLOT * sizeof(int));
  float* bucket_gate  = (float*)alloc((size_t)NSLOT * sizeof(float));
  int*   slot_of      = (int*)  alloc((size_t)NTOK * 2 * sizeof(int));
  unsigned short* xb  = (unsigned short*)alloc((size_t)NTOK * D_MODEL * 2);
  unsigned short* W1t = (unsigned short*)alloc((size_t)N_EXPERTS * D_MODEL * D_FF * 2);
  unsigned short* W2t = (unsigned short*)alloc((size_t)N_EXPERTS * D_MODEL * D_FF * 2);
  unsigned short* hb  = (unsigned short*)alloc((size_t)NSLOT * D_FF * 2);
  // y aliases W1t: W1t (64 MB) is dead once gemm1 completes; y needs
  // NSLOT*D_MODEL*4 = 64 MB. Sequential-stream ordering makes this safe.
  float* y = (float*)W1t;

  hipMemsetAsync(counts, 0, N_EXPERTS * sizeof(int), stream);

  convert_x_kernel<<<(NTOK * D_MODEL) / (4 * 256), 256, 0, stream>>>(x, xb);
  transpose_convert_kernel<<<dim3(D_FF / 32, D_MODEL / 32, N_EXPERTS), dim3(32, 8), 0, stream>>>(
      W1, W1t, D_MODEL, D_FF);
  router_kernel<<<NTOK, 64, 0, stream>>>(x, Wr, br, counts, topk_idx, topk_gate);
  prefix_kernel<<<1, 64, 0, stream>>>(counts, offsets, cursor, tile_e, tile_m);
  assign_kernel<<<NTOK / 256, 256, 0, stream>>>(topk_idx, topk_gate, cursor,
                                                bucket_token, bucket_gate, slot_of);
  gemm1_kernel<<<dim3(D_FF / BN, MAXTILES), 256, 0, stream>>>(
      xb, W1t, b1, bucket_token, offsets, counts, tile_e, tile_m, hb);
  transpose_convert_kernel<<<dim3(D_MODEL / 32, D_FF / 32, N_EXPERTS), dim3(32, 8), 0, stream>>>(
      W2, W2t, D_FF, D_MODEL);
  gemm2_kernel<<<dim3(D_MODEL / BN, MAXTILES), 256, 0, stream>>>(
      hb, W2t, b2, bucket_gate, offsets, counts, tile_e, tile_m, y);
  combine_kernel<<<NTOK, 256, 0, stream>>>(y, slot_of, out);
}

// Round 4
// 952.609 us; speedup vs baseline: 1.3026x; 1.0229x over previous
//
#include <hip/hip_runtime.h>
#include <cstdint>
#include <cstddef>

#define D_MODEL 1024
#define D_FF    4096
#define N_EXPERTS 8
#define TOPK_    2
#define NTOK    8192
#define NSLOT   (NTOK*TOPK_)
#define MAXTILES 136

#define BM 128
#define BN 128
#define BK 64

typedef __attribute__((ext_vector_type(8))) short bf16x8;
typedef __attribute__((ext_vector_type(4))) float f32x4;
typedef unsigned int u32;

__device__ __forceinline__ unsigned short f2bf(float f){
  union { float f; u32 u; } v; v.f = f;
  u32 u = v.u;
  u32 r = (u + 0x7FFFu + ((u >> 16) & 1u)) >> 16;
  return (unsigned short)r;
}

__device__ __forceinline__ float bf2f(unsigned short s){
  union { u32 u; float f; } v; v.u = (u32)s << 16; return v.f;
}

// gelu via Abramowitz-Stegun 7.1.26 erf, |err| <= 1.5e-7 abs.
__device__ __forceinline__ float gelu_fast(float x){
  float z = fabsf(x) * 0.70710678118654752f;
  float t = __builtin_amdgcn_rcpf(fmaf(0.3275911f, z, 1.0f));
  float poly = t * (0.254829592f + t * (-0.284496736f + t * (1.421413741f +
               t * (-1.453152027f + t * 1.061405429f))));
  float e = __expf(-z * z);
  float erf_abs = fmaf(-poly, e, 1.0f);
  float erfv = copysignf(erf_abs, x);
  return 0.5f * x * (1.0f + erfv);
}

__device__ __forceinline__ void gload_lds16(const void* g, void* l){
  __builtin_amdgcn_global_load_lds(
      (const __attribute__((address_space(1))) u32*)g,
      (__attribute__((address_space(3))) u32*)l, 16, 0, 0);
}

// ---------------- weight transpose: [E][R][C] fp32 -> [E][C][R] bf16 ----------
// 64x64 tiles; float4 global reads, ushort4 global writes (8 B/lane both ways).
// LDS tile is fp32 with +1 padding: write-phase reads are 2-way aliased (free).

__global__ __launch_bounds__(256) void transpose_convert_kernel(
    const float* __restrict__ in, unsigned short* __restrict__ out,
    int R, int C){
  __shared__ float tile[64][65];
  const int e  = blockIdx.z;
  const int c0 = blockIdx.x * 64;
  const int r0 = blockIdx.y * 64;
  const int tid = threadIdx.x;
  const size_t base = (size_t)e * R * C;
  {
    const int r  = tid >> 4;          // 0..15
    const int c4 = (tid & 15) * 4;    // 0..60
    #pragma unroll
    for (int it = 0; it < 4; it++){
      int rr = r + it * 16;
      float4 v = *(const float4*)(in + base + (size_t)(r0 + rr) * C + c0 + c4);
      tile[rr][c4 + 0] = v.x;
      tile[rr][c4 + 1] = v.y;
      tile[rr][c4 + 2] = v.z;
      tile[rr][c4 + 3] = v.w;
    }
  }
  __syncthreads();
  {
    const int c  = tid >> 4;          // 0..15
    const int r4 = (tid & 15) * 4;
    #pragma unroll
    for (int it = 0; it < 4; it++){
      int cc = c + it * 16;
      ushort4 w;
      w.x = f2bf(tile[r4 + 0][cc]);
      w.y = f2bf(tile[r4 + 1][cc]);
      w.z = f2bf(tile[r4 + 2][cc]);
      w.w = f2bf(tile[r4 + 3][cc]);
      *(ushort4*)(out + base + (size_t)(c0 + cc) * R + r0 + r4) = w;
    }
  }
}

// ---------------- router (also converts x -> bf16, single pass) --------------

__global__ __launch_bounds__(64) void router_kernel(
    const float* __restrict__ x,
    const float* __restrict__ Wr,
    const float* __restrict__ br,
    int* __restrict__ counts,
    int* __restrict__ topk_idx,
    float* __restrict__ topk_gate,
    unsigned short* __restrict__ xb){
  const int n = blockIdx.x;
  const int lane = threadIdx.x;      // 64 threads
  const float* xr = x + (size_t)n * D_MODEL;
  unsigned short* xbr = xb + (size_t)n * D_MODEL;
  float acc[N_EXPERTS];
  #pragma unroll
  for (int e = 0; e < N_EXPERTS; e++) acc[e] = 0.f;
  #pragma unroll
  for (int it = 0; it < 4; it++){
    int d = it * 256 + lane * 4;
    float4 v = *(const float4*)(xr + d);
    ushort4 w;
    w.x = f2bf(v.x); w.y = f2bf(v.y); w.z = f2bf(v.z); w.w = f2bf(v.w);
    *(ushort4*)(xbr + d) = w;
    const float* wr = Wr + (size_t)d * N_EXPERTS;
    const float* vv = &v.x;
    #pragma unroll
    for (int j = 0; j < 4; j++)
      #pragma unroll
      for (int e = 0; e < N_EXPERTS; e++)
        acc[e] = fmaf(vv[j], wr[j * N_EXPERTS + e], acc[e]);
  }
  #pragma unroll
  for (int e = 0; e < N_EXPERTS; e++){
    float v = acc[e];
    for (int o = 32; o > 0; o >>= 1) v += __shfl_xor(v, o, 64);
    acc[e] = v;
  }
  if (lane == 0){
    float logits[N_EXPERTS];
    float m = -1e30f;
    #pragma unroll
    for (int e = 0; e < N_EXPERTS; e++){
      logits[e] = acc[e] + br[e];
      m = fmaxf(m, logits[e]);
    }
    float p[N_EXPERTS]; float Z = 0.f;
    #pragma unroll
    for (int e = 0; e < N_EXPERTS; e++){ p[e] = expf(logits[e] - m); Z += p[e]; }
    #pragma unroll
    for (int e = 0; e < N_EXPERTS; e++) p[e] /= Z;
    int i0 = 0;
    #pragma unroll
    for (int e = 1; e < N_EXPERTS; e++) if (p[e] > p[i0]) i0 = e;
    int i1 = (i0 == 0) ? 1 : 0;
    #pragma unroll
    for (int e = 0; e < N_EXPERTS; e++){
      if (e == i0) continue;
      if (p[e] > p[i1]) i1 = e;
    }
    float s = p[i0] + p[i1] + 1e-9f;
    topk_idx[n * 2 + 0] = i0;
    topk_idx[n * 2 + 1] = i1;
    topk_gate[n * 2 + 0] = p[i0] / s;
    topk_gate[n * 2 + 1] = p[i1] / s;
    atomicAdd(&counts[i0], 1);
    atomicAdd(&counts[i1], 1);
  }
}

// ---------------- bookkeeping: offsets + tile table, parallel ----------------

__global__ __launch_bounds__(256) void prefix_kernel(
    const int* __restrict__ counts,
    int* __restrict__ offsets,
    int* __restrict__ cursor,
    int* __restrict__ tile_e,
    int* __restrict__ tile_m){
  __shared__ int scnt[N_EXPERTS];
  __shared__ int soff[N_EXPERTS];
  const int tid = threadIdx.x;
  if (tid < N_EXPERTS) scnt[tid] = counts[tid];
  __syncthreads();
  if (tid == 0){
    int o = 0;
    for (int e = 0; e < N_EXPERTS; e++){ soff[e] = o; o += scnt[e]; }
  }
  __syncthreads();
  if (tid < N_EXPERTS){ offsets[tid] = soff[tid]; cursor[tid] = soff[tid]; }
  if (tid < MAXTILES){
    int t = tid, te = -1, tm = 0, acc = 0;
    #pragma unroll
    for (int e = 0; e < N_EXPERTS; e++){
      int nt = (scnt[e] + BM - 1) / BM;
      if (te < 0 && t < acc + nt){ te = e; tm = t - acc; }
      acc += nt;
    }
    tile_e[tid] = te; tile_m[tid] = tm;
  }
}

__global__ void assign_kernel(const int* __restrict__ topk_idx,
                              const float* __restrict__ topk_gate,
                              int* __restrict__ cursor,
                              int* __restrict__ bucket_token,
                              float* __restrict__ bucket_gate,
                              int* __restrict__ slot_of){
  int n = blockIdx.x * blockDim.x + threadIdx.x;
  if (n >= NTOK) return;
  #pragma unroll
  for (int k = 0; k < TOPK_; k++){
    int e = topk_idx[n * 2 + k];
    float g = topk_gate[n * 2 + k];
    int s = atomicAdd(&cursor[e], 1);
    bucket_token[s] = n;
    bucket_gate[s] = g;
    slot_of[n * 2 + k] = s;
  }
}

// ---------------- grouped GEMM 1: h = gelu(x @ W1 + b1) ----------------
// XOR-swizzled LDS (SQ_LDS_BANK_CONFLICT verified 0).

__global__ __launch_bounds__(256, 3) void gemm1_kernel(
    const unsigned short* __restrict__ xb,
    const unsigned short* __restrict__ W1t,
    const float* __restrict__ b1,
    const int* __restrict__ bucket_token,
    const int* __restrict__ offsets,
    const int* __restrict__ counts,
    const int* __restrict__ tile_e,
    const int* __restrict__ tile_m,
    unsigned short* __restrict__ h){
  const int e = tile_e[blockIdx.y];
  if (e < 0) return;
  const int mtile = tile_m[blockIdx.y];
  const int ntile = blockIdx.x;
  const int count = counts[e];
  const int off = offsets[e];

  __shared__ unsigned short As[BM][BK];
  __shared__ unsigned short Bs[BN][BK];

  const int tid  = threadIdx.x;
  const int lane = tid & 63;
  const int wave = tid >> 6;

  const int srow   = wave * 8 + (lane >> 3);
  const int scol_l = (lane & 7) * 8;
  const int scol_g = (((lane & 7) ^ (lane >> 3)) * 8);

  int arow[4];
  #pragma unroll
  for (int j = 0; j < 4; j++){
    int m = mtile * BM + j * 32 + srow;
    arow[j] = bucket_token[off + min(m, count - 1)];
  }
  const unsigned short* Bbase = W1t + ((size_t)e * D_FF + (size_t)ntile * BN) * D_MODEL;

  const f32x4 zero = {0.f, 0.f, 0.f, 0.f};
  f32x4 acc[4][4];
  #pragma unroll
  for (int i = 0; i < 4; i++)
    #pragma unroll
    for (int j = 0; j < 4; j++) acc[i][j] = zero;

  const int wm = (wave >> 1) * 64;
  const int wn = (wave & 1) * 64;
  const int frag_m = lane & 15;

  for (int k0 = 0; k0 < D_MODEL; k0 += BK){
    __syncthreads();
    #pragma unroll
    for (int j = 0; j < 4; j++)
      gload_lds16(xb + (size_t)arow[j] * D_MODEL + k0 + scol_g, &As[j * 32 + srow][scol_l]);
    #pragma unroll
    for (int j = 0; j < 4; j++)
      gload_lds16(Bbase + (size_t)(j * 32 + srow) * D_MODEL + k0 + scol_g, &Bs[j * 32 + srow][scol_l]);
    __syncthreads();
    #pragma unroll
    for (int kk = 0; kk < BK; kk += 32){
      const int ck = ((((kk >> 3) + (lane >> 4)) ^ (lane & 7)) * 8);
      bf16x8 a[4], b[4];
      #pragma unroll
      for (int i = 0; i < 4; i++)
        a[i] = *(const bf16x8*)&As[wm + i * 16 + frag_m][ck];
      #pragma unroll
      for (int j = 0; j < 4; j++)
        b[j] = *(const bf16x8*)&Bs[wn + j * 16 + frag_m][ck];
      #pragma unroll
      for (int i = 0; i < 4; i++)
        #pragma unroll
        for (int j = 0; j < 4; j++)
          acc[i][j] = __builtin_amdgcn_mfma_f32_16x16x32_bf16(a[i], b[j], acc[i][j], 0, 0, 0);
    }
  }

  const float* bias = b1 + (size_t)e * D_FF + (size_t)ntile * BN;
  #pragma unroll
  for (int i = 0; i < 4; i++){
    #pragma unroll
    for (int r = 0; r < 4; r++){
      int mrel = wm + i * 16 + (lane >> 4) * 4 + r;
      int m = mtile * BM + mrel;
      if (m >= count) continue;
      size_t hrow = (size_t)(off + m) * D_FF + (size_t)ntile * BN;
      #pragma unroll
      for (int j = 0; j < 4; j++){
        int nrel = wn + j * 16 + (lane & 15);
        float v = acc[i][j][r] + bias[nrel];
        h[hrow + nrel] = f2bf(gelu_fast(v));
      }
    }
  }
}

// ---------------- grouped GEMM 2: y[slot] = bf16( g * (h @ W2 + b2) ) --------

__global__ __launch_bounds__(256, 3) void gemm2_kernel(
    const unsigned short* __restrict__ h,
    const unsigned short* __restrict__ W2t,   // [E][1024][4096]
    const float* __restrict__ b2,
    const float* __restrict__ bucket_gate,
    const int* __restrict__ offsets,
    const int* __restrict__ counts,
    const int* __restrict__ tile_e,
    const int* __restrict__ tile_m,
    unsigned short* __restrict__ y){
  const int e = tile_e[blockIdx.y];
  if (e < 0) return;
  const int mtile = tile_m[blockIdx.y];
  const int ntile = blockIdx.x;
  const int count = counts[e];
  const int off = offsets[e];

  __shared__ unsigned short As[BM][BK];
  __shared__ unsigned short Bs[BN][BK];

  const int tid  = threadIdx.x;
  const int lane = tid & 63;
  const int wave = tid >> 6;

  const int srow   = wave * 8 + (lane >> 3);
  const int scol_l = (lane & 7) * 8;
  const int scol_g = (((lane & 7) ^ (lane >> 3)) * 8);

  size_t aslot[4];
  #pragma unroll
  for (int j = 0; j < 4; j++){
    int m = mtile * BM + j * 32 + srow;
    aslot[j] = (size_t)(off + min(m, count - 1));
  }
  const unsigned short* Bbase = W2t + ((size_t)e * D_MODEL + (size_t)ntile * BN) * D_FF;

  const f32x4 zero = {0.f, 0.f, 0.f, 0.f};
  f32x4 acc[4][4];
  #pragma unroll
  for (int i = 0; i < 4; i++)
    #pragma unroll
    for (int j = 0; j < 4; j++) acc[i][j] = zero;

  const int wm = (wave >> 1) * 64;
  const int wn = (wave & 1) * 64;
  const int frag_m = lane & 15;

  for (int k0 = 0; k0 < D_FF; k0 += BK){
    __syncthreads();
    #pragma unroll
    for (int j = 0; j < 4; j++)
      gload_lds16(h + aslot[j] * D_FF + k0 + scol_g, &As[j * 32 + srow][scol_l]);
    #pragma unroll
    for (int j = 0; j < 4; j++)
      gload_lds16(Bbase + (size_t)(j * 32 + srow) * D_FF + k0 + scol_g, &Bs[j * 32 + srow][scol_l]);
    __syncthreads();
    #pragma unroll
    for (int kk = 0; kk < BK; kk += 32){
      const int ck = ((((kk >> 3) + (lane >> 4)) ^ (lane & 7)) * 8);
      bf16x8 a[4], b[4];
      #pragma unroll
      for (int i = 0; i < 4; i++)
        a[i] = *(const bf16x8*)&As[wm + i * 16 + frag_m][ck];
      #pragma unroll
      for (int j = 0; j < 4; j++)
        b[j] = *(const bf16x8*)&Bs[wn + j * 16 + frag_m][ck];
      #pragma unroll
      for (int i = 0; i < 4; i++)
        #pragma unroll
        for (int j = 0; j < 4; j++)
          acc[i][j] = __builtin_amdgcn_mfma_f32_16x16x32_bf16(a[i], b[j], acc[i][j], 0, 0, 0);
    }
  }

  const float* bias = b2 + (size_t)e * D_MODEL + (size_t)ntile * BN;
  #pragma unroll
  for (int i = 0; i < 4; i++){
    #pragma unroll
    for (int r = 0; r < 4; r++){
      int mrel = wm + i * 16 + (lane >> 4) * 4 + r;
      int m = mtile * BM + mrel;
      if (m >= count) continue;
      int slot = off + m;
      float g = bucket_gate[slot];
      unsigned short* yrow = y + (size_t)slot * D_MODEL + (size_t)ntile * BN;
      #pragma unroll
      for (int j = 0; j < 4; j++){
        int nrel = wn + j * 16 + (lane & 15);
        yrow[nrel] = f2bf(g * (acc[i][j][r] + bias[nrel]));
      }
    }
  }
}

// ---------------- combine: out[t] = y[slot0(t)] + y[slot1(t)] ----------------

__global__ __launch_bounds__(256) void combine_kernel(
    const unsigned short* __restrict__ y,
    const int* __restrict__ slot_of,
    float* __restrict__ out){
  const int t = blockIdx.x;
  const int d = threadIdx.x * 4;
  const int s0 = slot_of[t * 2 + 0];
  const int s1 = slot_of[t * 2 + 1];
  uint2 a = *(const uint2*)(y + (size_t)s0 * D_MODEL + d);
  uint2 b = *(const uint2*)(y + (size_t)s1 * D_MODEL + d);
  float4 r;
  r.x = bf2f((unsigned short)(a.x & 0xffff)) + bf2f((unsigned short)(b.x & 0xffff));
  r.y = bf2f((unsigned short)(a.x >> 16))    + bf2f((unsigned short)(b.x >> 16));
  r.z = bf2f((unsigned short)(a.y & 0xffff)) + bf2f((unsigned short)(b.y & 0xffff));
  r.w = bf2f((unsigned short)(a.y >> 16))    + bf2f((unsigned short)(b.y >> 16));
  *(float4*)(out + (size_t)t * D_MODEL + d) = r;
}

// ---------------- launch ----------------

extern "C" void kernel_launch(void* const* d_in, const int* in_sizes, int n_in,
                              void* d_out, int out_size, void* d_ws, size_t ws_size,
                              hipStream_t stream) {
  (void)in_sizes; (void)n_in; (void)ws_size; (void)out_size;
  const float* x  = (const float*)d_in[0];
  const float* Wr = (const float*)d_in[1];
  const float* br = (const float*)d_in[2];
  const float* W1 = (const float*)d_in[3];
  const float* b1 = (const float*)d_in[4];
  const float* W2 = (const float*)d_in[5];
  const float* b2 = (const float*)d_in[6];
  float* out = (float*)d_out;

  char* ws = (char*)d_ws;
  size_t p = 0;
  auto alloc = [&](size_t bytes) -> void* {
    void* r = ws + p;
    p = (p + bytes + 255) & ~(size_t)255;
    return r;
  };

  int*   counts       = (int*)  alloc(N_EXPERTS * sizeof(int));
  int*   offsets      = (int*)  alloc(N_EXPERTS * sizeof(int));
  int*   cursor       = (int*)  alloc(N_EXPERTS * sizeof(int));
  int*   tile_e       = (int*)  alloc(MAXTILES * sizeof(int));
  int*   tile_m       = (int*)  alloc(MAXTILES * sizeof(int));
  int*   topk_idx     = (int*)  alloc((size_t)NTOK * 2 * sizeof(int));
  float* topk_gate    = (float*)alloc((size_t)NTOK * 2 * sizeof(float));
  int*   bucket_token = (int*)  alloc((size_t)NSLOT * sizeof(int));
  float* bucket_gate  = (float*)alloc((size_t)NSLOT * sizeof(float));
  int*   slot_of      = (int*)  alloc((size_t)NTOK * 2 * sizeof(int));
  unsigned short* xb  = (unsigned short*)alloc((size_t)NTOK * D_MODEL * 2);
  unsigned short* W1t = (unsigned short*)alloc((size_t)N_EXPERTS * D_MODEL * D_FF * 2);
  unsigned short* W2t = (unsigned short*)alloc((size_t)N_EXPERTS * D_MODEL * D_FF * 2);
  unsigned short* hb  = (unsigned short*)alloc((size_t)NSLOT * D_FF * 2);
  // y (bf16, 32 MB) aliases W1t (64 MB): W1t is dead once gemm1 completes.
  unsigned short* y = W1t;

  hipMemsetAsync(counts, 0, N_EXPERTS * sizeof(int), stream);

  // Transposes FIRST so nothing streams between gemm1 and gemm2 (keeps h
  // L3-resident for gemm2), and gemm1 reads recently-written xb/W1t.
  transpose_convert_kernel<<<dim3(D_MODEL / 64, D_FF / 64, N_EXPERTS), 256, 0, stream>>>(
      W2, W2t, D_FF, D_MODEL);
  transpose_convert_kernel<<<dim3(D_FF / 64, D_MODEL / 64, N_EXPERTS), 256, 0, stream>>>(
      W1, W1t, D_MODEL, D_FF);
  router_kernel<<<NTOK, 64, 0, stream>>>(x, Wr, br, counts, topk_idx, topk_gate, xb);
  prefix_kernel<<<1, 256, 0, stream>>>(counts, offsets, cursor, tile_e, tile_m);
  assign_kernel<<<NTOK / 256, 256, 0, stream>>>(topk_idx, topk_gate, cursor,
                                                bucket_token, bucket_gate, slot_of);
  gemm1_kernel<<<dim3(D_FF / BN, MAXTILES), 256, 0, stream>>>(
      xb, W1t, b1, bucket_token, offsets, counts, tile_e, tile_m, hb);
  gemm2_kernel<<<dim3(D_MODEL / BN, MAXTILES), 256, 0, stream>>>(
      hb, W2t, b2, bucket_gate, offsets, counts, tile_e, tile_m, y);
  combine_kernel<<<NTOK, 256, 0, stream>>>(y, slot_of, out);
}